// Round 4
// baseline (1037.236 us; speedup 1.0000x reference)
//
#include <hip/hip_runtime.h>

#define N_NODES 12288
#define IN_F    256
#define OUT_F   64
#define KSPLIT  8
#define MT      64
#define KC      (N_NODES / KSPLIT)   /* 1536 */
#define STEPS   (KC / 32)            /* 48 */

typedef __attribute__((ext_vector_type(8))) short bf16x8;
typedef __attribute__((ext_vector_type(4))) float f32x4;

__device__ __forceinline__ unsigned short f2bf(float f) {
    union { float f; unsigned int i; } v; v.f = f;
    unsigned int x = v.i;
    unsigned int r = x + 0x7FFFu + ((x >> 16) & 1u);  // RNE
    return (unsigned short)(r >> 16);
}

// ---------------- kernel 0: adj int32 {0,1} -> int8, pure fill-shaped stream.
// 16 B/lane coalesced reads, 4 B/lane coalesced writes, grid-stride.
// 604 MB read + 151 MB write ~= 120 us at the 6.4 TB/s the fills prove.
__global__ __launch_bounds__(256) void k_pack(const int* __restrict__ adj,
                                              unsigned int* __restrict__ adj8) {
    const size_t total  = (size_t)N_NODES * N_NODES / 4;   // 37748736 int4-chunks
    const size_t stride = (size_t)2048 * 256;              // 524288 threads
    size_t i = (size_t)blockIdx.x * 256 + threadIdx.x;
    #pragma unroll 2
    for (; i < total; i += stride) {
        int4 a = ((const int4*)adj)[i];
        adj8[i] = (unsigned)a.x | ((unsigned)a.y << 8) |
                  ((unsigned)a.z << 16) | ((unsigned)a.w << 24);
    }
}

// ---------------- kernel 1: hT[n][i] = bf16( (x @ W)[i][n] )  via MFMA
__global__ __launch_bounds__(256) void k_hT(const float* __restrict__ x,
                                            const float* __restrict__ W,
                                            unsigned short* __restrict__ hT) {
    __shared__ unsigned short WT[OUT_F][IN_F + 8];   // WT[n][k] = bf16(W[k][n])
    int tid = threadIdx.x;
    for (int idx = tid; idx < IN_F * OUT_F; idx += 256) {
        int k = idx >> 6, n = idx & 63;
        WT[n][k] = f2bf(W[idx]);
    }
    __syncthreads();

    int lane = tid & 63, wave = tid >> 6;
    int q = lane >> 4, ml = lane & 15;
    int i0 = blockIdx.x * MT;
    int row = i0 + 16 * wave + ml;
    const float* xr = x + (size_t)row * IN_F + 8 * q;

    f32x4 acc[4];
    #pragma unroll
    for (int nt = 0; nt < 4; ++nt) acc[nt] = (f32x4){0.f, 0.f, 0.f, 0.f};

    #pragma unroll
    for (int kk = 0; kk < IN_F; kk += 32) {
        float4 x0 = *(const float4*)(xr + kk);
        float4 x1 = *(const float4*)(xr + kk + 4);
        union { bf16x8 v; unsigned short u[8]; } A;
        A.u[0] = f2bf(x0.x); A.u[1] = f2bf(x0.y); A.u[2] = f2bf(x0.z); A.u[3] = f2bf(x0.w);
        A.u[4] = f2bf(x1.x); A.u[5] = f2bf(x1.y); A.u[6] = f2bf(x1.z); A.u[7] = f2bf(x1.w);
        #pragma unroll
        for (int nt = 0; nt < 4; ++nt) {
            bf16x8 bv = *(const bf16x8*)&WT[16 * nt + ml][kk + 8 * q];
            acc[nt] = __builtin_amdgcn_mfma_f32_16x16x32_bf16(A.v, bv, acc[nt], 0, 0, 0);
        }
    }

    #pragma unroll
    for (int nt = 0; nt < 4; ++nt) {
        ushort4 o;
        o.x = f2bf(acc[nt][0]); o.y = f2bf(acc[nt][1]);
        o.z = f2bf(acc[nt][2]); o.w = f2bf(acc[nt][3]);
        *(ushort4*)&hT[(size_t)(16 * nt + ml) * N_NODES + i0 + 16 * wave + 4 * q] = o;
    }
}

// ---------------- kernel 2: streaming adj8 @ h (R2 skeleton, 4x less adj traffic)
// A-fragment: lane(ml,q) loads 8 adj8 bytes (uint2), unpacks byte->bf16 in regs
// ((b0|b1<<16)*0x3F80). B-fragment: dwordx4 from L1/L2-resident hT.
// 2-deep register pipeline, no LDS, no barriers. Degree via ones-MFMA (exact).
__global__ __launch_bounds__(256) void k_spmm(const unsigned char* __restrict__ adj8,
                                              const unsigned short* __restrict__ hT,
                                              float* __restrict__ s_part,
                                              float* __restrict__ deg_part) {
    const int tid  = threadIdx.x;
    const int lane = tid & 63;
    const int wave = tid >> 6;
    const int q    = lane >> 4;
    const int ml   = lane & 15;
    const int i0   = blockIdx.x * MT;
    const int ks   = blockIdx.y;
    const int k0   = ks * KC;
    const int row  = i0 + 16 * wave + ml;

    const unsigned char*  ap = adj8 + (size_t)row * N_NODES + k0 + 8 * q;
    const unsigned short* bp = hT + (size_t)ml * N_NODES + k0 + 8 * q;

    union { bf16x8 v; unsigned short u[8]; } ones;
    #pragma unroll
    for (int i = 0; i < 8; ++i) ones.u[i] = 0x3F80;

    f32x4 acc[4], accd;
    #pragma unroll
    for (int nt = 0; nt < 4; ++nt) acc[nt] = (f32x4){0.f, 0.f, 0.f, 0.f};
    accd = (f32x4){0.f, 0.f, 0.f, 0.f};

#define LOADS(s, AA, B0, B1, B2, B3) do {                                      \
    AA = *(const uint2*)(ap + 32 * (size_t)(s));                               \
    const unsigned short* bq = bp + 32 * (s);                                  \
    B0 = *(const uint4*)(bq);                                                  \
    B1 = *(const uint4*)(bq + (size_t)16 * N_NODES);                           \
    B2 = *(const uint4*)(bq + (size_t)32 * N_NODES);                           \
    B3 = *(const uint4*)(bq + (size_t)48 * N_NODES);                           \
} while (0)

#define COMP(AA, B0, B1, B2, B3) do {                                          \
    unsigned int u_ = AA.x, v_ = AA.y;                                         \
    union { bf16x8 v; unsigned int w[4]; } av_;                                \
    av_.w[0] = ((u_ & 0xFFu)         | ((u_ & 0xFF00u) << 8)) * 0x3F80u;       \
    av_.w[1] = (((u_ >> 16) & 0xFFu) | ((u_ >> 24) << 16))    * 0x3F80u;       \
    av_.w[2] = ((v_ & 0xFFu)         | ((v_ & 0xFF00u) << 8)) * 0x3F80u;       \
    av_.w[3] = (((v_ >> 16) & 0xFFu) | ((v_ >> 24) << 16))    * 0x3F80u;       \
    acc[0] = __builtin_amdgcn_mfma_f32_16x16x32_bf16(av_.v, *(const bf16x8*)&B0, acc[0], 0, 0, 0); \
    acc[1] = __builtin_amdgcn_mfma_f32_16x16x32_bf16(av_.v, *(const bf16x8*)&B1, acc[1], 0, 0, 0); \
    acc[2] = __builtin_amdgcn_mfma_f32_16x16x32_bf16(av_.v, *(const bf16x8*)&B2, acc[2], 0, 0, 0); \
    acc[3] = __builtin_amdgcn_mfma_f32_16x16x32_bf16(av_.v, *(const bf16x8*)&B3, acc[3], 0, 0, 0); \
    accd   = __builtin_amdgcn_mfma_f32_16x16x32_bf16(av_.v, ones.v,              accd,   0, 0, 0); \
} while (0)

    uint2 aA, aB;
    uint4 b0A, b1A, b2A, b3A;
    uint4 b0B, b1B, b2B, b3B;

    LOADS(0, aA, b0A, b1A, b2A, b3A);
    for (int s = 0; s < STEPS - 2; s += 2) {
        LOADS(s + 1, aB, b0B, b1B, b2B, b3B);
        COMP(aA, b0A, b1A, b2A, b3A);
        LOADS(s + 2, aA, b0A, b1A, b2A, b3A);
        COMP(aB, b0B, b1B, b2B, b3B);
    }
    LOADS(STEPS - 1, aB, b0B, b1B, b2B, b3B);
    COMP(aA, b0A, b1A, b2A, b3A);
    COMP(aB, b0B, b1B, b2B, b3B);

#undef LOADS
#undef COMP

    // epilogue: non-atomic partial store (each block owns its 64x64 region of slice ks)
    float* sp = s_part + (size_t)ks * ((size_t)N_NODES * OUT_F);
    #pragma unroll
    for (int nt = 0; nt < 4; ++nt) {
        #pragma unroll
        for (int rr = 0; rr < 4; ++rr) {
            int orow = i0 + 16 * wave + 4 * q + rr;   // C layout: row = quad*4+reg
            int ocol = 16 * nt + ml;                  // col = lane&15
            sp[(size_t)orow * OUT_F + ocol] = acc[nt][rr];
        }
    }

    // degree: C[m][n] of ones-MFMA is row-degree in every column; take col 0 (ml==0 lanes)
    if (ml == 0) {
        #pragma unroll
        for (int rr = 0; rr < 4; ++rr)
            deg_part[ks * N_NODES + i0 + 16 * wave + 4 * q + rr] = accd[rr];
    }
}

// ---------------- kernel 3: out = elu( sum_p s_part / sum_p deg_part ), fp32
__global__ __launch_bounds__(256) void k_out(const float* __restrict__ s_part,
                                             const float* __restrict__ deg_part,
                                             float* __restrict__ out) {
    int idx = blockIdx.x * 256 + threadIdx.x;
    int i = idx >> 6;
    float s = 0.f, deg = 0.f;
    #pragma unroll
    for (int p = 0; p < KSPLIT; ++p) {
        s   += s_part[(size_t)p * ((size_t)N_NODES * OUT_F) + idx];
        deg += deg_part[p * N_NODES + i];
    }
    float v = (deg > 0.5f) ? (s / deg) : 0.f;
    out[idx] = (v > 0.f) ? v : expm1f(v);
}

extern "C" void kernel_launch(void* const* d_in, const int* in_sizes, int n_in,
                              void* d_out, int out_size, void* d_ws, size_t ws_size,
                              hipStream_t stream) {
    const int*   adj = (const int*)d_in[0];
    const float* x   = (const float*)d_in[1];   // fp32
    const float* W   = (const float*)d_in[2];   // fp32
    // d_in[3] (a) provably cancels out of the output — unused.
    float* out = (float*)d_out;                 // fp32

    char* ws = (char*)d_ws;
    const size_t hT_bytes  = (size_t)N_NODES * OUT_F * 2;                 // 1.5 MB
    const size_t sp_bytes  = (size_t)KSPLIT * N_NODES * OUT_F * 4;        // 25.2 MB
    const size_t dp_bytes  = (size_t)KSPLIT * N_NODES * 4;                // 0.4 MB
    unsigned short* hT     = (unsigned short*)ws;
    float* s_part          = (float*)(ws + hT_bytes);
    float* deg_part        = (float*)(ws + hT_bytes + sp_bytes);
    unsigned char* adj8    = (unsigned char*)(ws + hT_bytes + sp_bytes + dp_bytes);
    // adj8: 151 MB; total ~178 MB of d_ws (fill shows 2.4 GB available)

    k_pack<<<dim3(2048),                  dim3(256), 0, stream>>>(adj, (unsigned int*)adj8);
    k_hT  <<<dim3(N_NODES / MT),          dim3(256), 0, stream>>>(x, W, hT);
    k_spmm<<<dim3(N_NODES / MT, KSPLIT),  dim3(256), 0, stream>>>(adj8, hT, s_part, deg_part);
    k_out <<<dim3(N_NODES * OUT_F / 256), dim3(256), 0, stream>>>(s_part, deg_part, out);
}

// Round 5
// 961.246 us; speedup vs baseline: 1.0791x; 1.0791x over previous
//
#include <hip/hip_runtime.h>

#define N_NODES 12288
#define IN_F    256
#define OUT_F   64
#define KSPLIT  8
#define MT      64
#define KC      (N_NODES / KSPLIT)   /* 1536 */
#define STEPS   (KC / 32)            /* 48 */
#define NSTRH   (N_NODES + 32)       /* hT row stride in shorts: 24640 B = 64 mod 4096 */
#define NSTR8   (N_NODES + 64)       /* adj8 row stride in bytes: 12352 = 64 mod 4096 */

typedef __attribute__((ext_vector_type(8))) short bf16x8;
typedef __attribute__((ext_vector_type(4))) float f32x4;

__device__ __forceinline__ unsigned short f2bf(float f) {
    union { float f; unsigned int i; } v; v.f = f;
    unsigned int x = v.i;
    unsigned int r = x + 0x7FFFu + ((x >> 16) & 1u);  // RNE
    return (unsigned short)(r >> 16);
}

// ---------------- kernel 0: adj int32 {0,1} -> int8 rows with +64B padded stride.
// One block per row; reads linear int4, writes linear u32 within the row.
// The padded output stride de-aliases the 16-row gathers in k_spmm.
__global__ __launch_bounds__(256) void k_pack(const int* __restrict__ adj,
                                              unsigned char* __restrict__ adj8) {
    const int row = blockIdx.x;
    const int t   = threadIdx.x;
    const int4* src = (const int4*)(adj + (size_t)row * N_NODES);
    unsigned int* dst = (unsigned int*)(adj8 + (size_t)row * NSTR8);
    #pragma unroll
    for (int j = 0; j < (N_NODES / 4) / 256; ++j) {   // 12 iters
        int i = t + 256 * j;
        int4 a = src[i];
        dst[i] = (unsigned)a.x | ((unsigned)a.y << 8) |
                 ((unsigned)a.z << 16) | ((unsigned)a.w << 24);
    }
}

// ---------------- kernel 1: hT[n][i] = bf16( (x @ W)[i][n] ), padded row stride
__global__ __launch_bounds__(256) void k_hT(const float* __restrict__ x,
                                            const float* __restrict__ W,
                                            unsigned short* __restrict__ hT) {
    __shared__ unsigned short WT[OUT_F][IN_F + 8];   // WT[n][k] = bf16(W[k][n])
    int tid = threadIdx.x;
    for (int idx = tid; idx < IN_F * OUT_F; idx += 256) {
        int k = idx >> 6, n = idx & 63;
        WT[n][k] = f2bf(W[idx]);
    }
    __syncthreads();

    int lane = tid & 63, wave = tid >> 6;
    int q = lane >> 4, ml = lane & 15;
    int i0 = blockIdx.x * MT;
    int row = i0 + 16 * wave + ml;
    const float* xr = x + (size_t)row * IN_F + 8 * q;

    f32x4 acc[4];
    #pragma unroll
    for (int nt = 0; nt < 4; ++nt) acc[nt] = (f32x4){0.f, 0.f, 0.f, 0.f};

    #pragma unroll
    for (int kk = 0; kk < IN_F; kk += 32) {
        float4 x0 = *(const float4*)(xr + kk);
        float4 x1 = *(const float4*)(xr + kk + 4);
        union { bf16x8 v; unsigned short u[8]; } A;
        A.u[0] = f2bf(x0.x); A.u[1] = f2bf(x0.y); A.u[2] = f2bf(x0.z); A.u[3] = f2bf(x0.w);
        A.u[4] = f2bf(x1.x); A.u[5] = f2bf(x1.y); A.u[6] = f2bf(x1.z); A.u[7] = f2bf(x1.w);
        #pragma unroll
        for (int nt = 0; nt < 4; ++nt) {
            bf16x8 bv = *(const bf16x8*)&WT[16 * nt + ml][kk + 8 * q];
            acc[nt] = __builtin_amdgcn_mfma_f32_16x16x32_bf16(A.v, bv, acc[nt], 0, 0, 0);
        }
    }

    #pragma unroll
    for (int nt = 0; nt < 4; ++nt) {
        ushort4 o;
        o.x = f2bf(acc[nt][0]); o.y = f2bf(acc[nt][1]);
        o.z = f2bf(acc[nt][2]); o.w = f2bf(acc[nt][3]);
        *(ushort4*)&hT[(size_t)(16 * nt + ml) * NSTRH + i0 + 16 * wave + 4 * q] = o;
    }
}

// ---------------- kernel 2: streaming adj8 @ h (R4 skeleton + de-aliased strides)
__global__ __launch_bounds__(256) void k_spmm(const unsigned char* __restrict__ adj8,
                                              const unsigned short* __restrict__ hT,
                                              float* __restrict__ s_part,
                                              float* __restrict__ deg_part) {
    const int tid  = threadIdx.x;
    const int lane = tid & 63;
    const int wave = tid >> 6;
    const int q    = lane >> 4;
    const int ml   = lane & 15;
    const int i0   = blockIdx.x * MT;
    const int ks   = blockIdx.y;
    const int k0   = ks * KC;
    const int row  = i0 + 16 * wave + ml;

    const unsigned char*  ap = adj8 + (size_t)row * NSTR8 + k0 + 8 * q;
    const unsigned short* bp = hT + (size_t)ml * NSTRH + k0 + 8 * q;

    union { bf16x8 v; unsigned short u[8]; } ones;
    #pragma unroll
    for (int i = 0; i < 8; ++i) ones.u[i] = 0x3F80;

    f32x4 acc[4], accd;
    #pragma unroll
    for (int nt = 0; nt < 4; ++nt) acc[nt] = (f32x4){0.f, 0.f, 0.f, 0.f};
    accd = (f32x4){0.f, 0.f, 0.f, 0.f};

#define LOADS(s, AA, B0, B1, B2, B3) do {                                      \
    AA = *(const uint2*)(ap + 32 * (size_t)(s));                               \
    const unsigned short* bq = bp + 32 * (s);                                  \
    B0 = *(const uint4*)(bq);                                                  \
    B1 = *(const uint4*)(bq + (size_t)16 * NSTRH);                             \
    B2 = *(const uint4*)(bq + (size_t)32 * NSTRH);                             \
    B3 = *(const uint4*)(bq + (size_t)48 * NSTRH);                             \
} while (0)

#define COMP(AA, B0, B1, B2, B3) do {                                          \
    unsigned int u_ = AA.x, v_ = AA.y;                                         \
    union { bf16x8 v; unsigned int w[4]; } av_;                                \
    av_.w[0] = ((u_ & 0xFFu)         | ((u_ & 0xFF00u) << 8)) * 0x3F80u;       \
    av_.w[1] = (((u_ >> 16) & 0xFFu) | ((u_ >> 24) << 16))    * 0x3F80u;       \
    av_.w[2] = ((v_ & 0xFFu)         | ((v_ & 0xFF00u) << 8)) * 0x3F80u;       \
    av_.w[3] = (((v_ >> 16) & 0xFFu) | ((v_ >> 24) << 16))    * 0x3F80u;       \
    acc[0] = __builtin_amdgcn_mfma_f32_16x16x32_bf16(av_.v, *(const bf16x8*)&B0, acc[0], 0, 0, 0); \
    acc[1] = __builtin_amdgcn_mfma_f32_16x16x32_bf16(av_.v, *(const bf16x8*)&B1, acc[1], 0, 0, 0); \
    acc[2] = __builtin_amdgcn_mfma_f32_16x16x32_bf16(av_.v, *(const bf16x8*)&B2, acc[2], 0, 0, 0); \
    acc[3] = __builtin_amdgcn_mfma_f32_16x16x32_bf16(av_.v, *(const bf16x8*)&B3, acc[3], 0, 0, 0); \
    accd   = __builtin_amdgcn_mfma_f32_16x16x32_bf16(av_.v, ones.v,              accd,   0, 0, 0); \
} while (0)

    uint2 aA, aB;
    uint4 b0A, b1A, b2A, b3A;
    uint4 b0B, b1B, b2B, b3B;

    LOADS(0, aA, b0A, b1A, b2A, b3A);
    for (int s = 0; s < STEPS - 2; s += 2) {
        LOADS(s + 1, aB, b0B, b1B, b2B, b3B);
        COMP(aA, b0A, b1A, b2A, b3A);
        LOADS(s + 2, aA, b0A, b1A, b2A, b3A);
        COMP(aB, b0B, b1B, b2B, b3B);
    }
    LOADS(STEPS - 1, aB, b0B, b1B, b2B, b3B);
    COMP(aA, b0A, b1A, b2A, b3A);
    COMP(aB, b0B, b1B, b2B, b3B);

#undef LOADS
#undef COMP

    // epilogue: non-atomic partial store (each block owns its 64x64 region of slice ks)
    float* sp = s_part + (size_t)ks * ((size_t)N_NODES * OUT_F);
    #pragma unroll
    for (int nt = 0; nt < 4; ++nt) {
        #pragma unroll
        for (int rr = 0; rr < 4; ++rr) {
            int orow = i0 + 16 * wave + 4 * q + rr;   // C layout: row = quad*4+reg
            int ocol = 16 * nt + ml;                  // col = lane&15
            sp[(size_t)orow * OUT_F + ocol] = acc[nt][rr];
        }
    }

    // degree: C[m][n] of ones-MFMA is row-degree in every column; take col 0 (ml==0 lanes)
    if (ml == 0) {
        #pragma unroll
        for (int rr = 0; rr < 4; ++rr)
            deg_part[ks * N_NODES + i0 + 16 * wave + 4 * q + rr] = accd[rr];
    }
}

// ---------------- kernel 3: out = elu( sum_p s_part / sum_p deg_part ), fp32
__global__ __launch_bounds__(256) void k_out(const float* __restrict__ s_part,
                                             const float* __restrict__ deg_part,
                                             float* __restrict__ out) {
    int idx = blockIdx.x * 256 + threadIdx.x;
    int i = idx >> 6;
    float s = 0.f, deg = 0.f;
    #pragma unroll
    for (int p = 0; p < KSPLIT; ++p) {
        s   += s_part[(size_t)p * ((size_t)N_NODES * OUT_F) + idx];
        deg += deg_part[p * N_NODES + i];
    }
    float v = (deg > 0.5f) ? (s / deg) : 0.f;
    out[idx] = (v > 0.f) ? v : expm1f(v);
}

extern "C" void kernel_launch(void* const* d_in, const int* in_sizes, int n_in,
                              void* d_out, int out_size, void* d_ws, size_t ws_size,
                              hipStream_t stream) {
    const int*   adj = (const int*)d_in[0];
    const float* x   = (const float*)d_in[1];   // fp32
    const float* W   = (const float*)d_in[2];   // fp32
    // d_in[3] (a) provably cancels out of the output — unused.
    float* out = (float*)d_out;                 // fp32

    char* ws = (char*)d_ws;
    const size_t hT_bytes  = (size_t)OUT_F * NSTRH * 2;                   // ~1.58 MB
    const size_t sp_bytes  = (size_t)KSPLIT * N_NODES * OUT_F * 4;        // 25.2 MB
    const size_t dp_bytes  = (size_t)KSPLIT * N_NODES * 4;                // 0.4 MB
    unsigned short* hT     = (unsigned short*)ws;
    float* s_part          = (float*)(ws + hT_bytes);
    float* deg_part        = (float*)(ws + hT_bytes + sp_bytes);
    unsigned char* adj8    = (unsigned char*)(ws + hT_bytes + sp_bytes + dp_bytes);
    // adj8: 12288 * 12352 B ~= 151.8 MB; total ~179 MB of d_ws

    k_pack<<<dim3(N_NODES),               dim3(256), 0, stream>>>(adj, adj8);
    k_hT  <<<dim3(N_NODES / MT),          dim3(256), 0, stream>>>(x, W, hT);
    k_spmm<<<dim3(N_NODES / MT, KSPLIT),  dim3(256), 0, stream>>>(adj8, hT, s_part, deg_part);
    k_out <<<dim3(N_NODES * OUT_F / 256), dim3(256), 0, stream>>>(s_part, deg_part, out);
}

// Round 6
// 833.692 us; speedup vs baseline: 1.2441x; 1.1530x over previous
//
#include <hip/hip_runtime.h>

#define N_NODES 12288
#define IN_F    256
#define OUT_F   64
#define KSPLIT  8
#define MT      64
#define KC      (N_NODES / KSPLIT)   /* 1536 */
#define BK      128
#define NSTEP   (KC / BK)            /* 12 */
#define NSTRH   (N_NODES + 32)       /* hT row stride in shorts: 24640 B = 64 mod 4096 */
#define LPAD    8                    /* LDS row pad (shorts) */

typedef __attribute__((ext_vector_type(8))) short bf16x8;
typedef __attribute__((ext_vector_type(4))) float f32x4;

__device__ __forceinline__ unsigned short f2bf(float f) {
    union { float f; unsigned int i; } v; v.f = f;
    unsigned int x = v.i;
    unsigned int r = x + 0x7FFFu + ((x >> 16) & 1u);  // RNE
    return (unsigned short)(r >> 16);
}

// ---------------- kernel 1: hT[n][i] = bf16( (x @ W)[i][n] ), padded row stride
__global__ __launch_bounds__(256) void k_hT(const float* __restrict__ x,
                                            const float* __restrict__ W,
                                            unsigned short* __restrict__ hT) {
    __shared__ unsigned short WT[OUT_F][IN_F + 8];   // WT[n][k] = bf16(W[k][n])
    int tid = threadIdx.x;
    for (int idx = tid; idx < IN_F * OUT_F; idx += 256) {
        int k = idx >> 6, n = idx & 63;
        WT[n][k] = f2bf(W[idx]);
    }
    __syncthreads();

    int lane = tid & 63, wave = tid >> 6;
    int q = lane >> 4, ml = lane & 15;
    int i0 = blockIdx.x * MT;
    int row = i0 + 16 * wave + ml;
    const float* xr = x + (size_t)row * IN_F + 8 * q;

    f32x4 acc[4];
    #pragma unroll
    for (int nt = 0; nt < 4; ++nt) acc[nt] = (f32x4){0.f, 0.f, 0.f, 0.f};

    #pragma unroll
    for (int kk = 0; kk < IN_F; kk += 32) {
        float4 x0 = *(const float4*)(xr + kk);
        float4 x1 = *(const float4*)(xr + kk + 4);
        union { bf16x8 v; unsigned short u[8]; } A;
        A.u[0] = f2bf(x0.x); A.u[1] = f2bf(x0.y); A.u[2] = f2bf(x0.z); A.u[3] = f2bf(x0.w);
        A.u[4] = f2bf(x1.x); A.u[5] = f2bf(x1.y); A.u[6] = f2bf(x1.z); A.u[7] = f2bf(x1.w);
        #pragma unroll
        for (int nt = 0; nt < 4; ++nt) {
            bf16x8 bv = *(const bf16x8*)&WT[16 * nt + ml][kk + 8 * q];
            acc[nt] = __builtin_amdgcn_mfma_f32_16x16x32_bf16(A.v, bv, acc[nt], 0, 0, 0);
        }
    }

    #pragma unroll
    for (int nt = 0; nt < 4; ++nt) {
        ushort4 o;
        o.x = f2bf(acc[nt][0]); o.y = f2bf(acc[nt][1]);
        o.z = f2bf(acc[nt][2]); o.w = f2bf(acc[nt][3]);
        *(ushort4*)&hT[(size_t)(16 * nt + ml) * NSTRH + i0 + 16 * wave + 4 * q] = o;
    }
}

// ---------------- kernel 2: LDS-GEMM on adj (int32, direct) with fully-coalesced
// long-run staging. Per wave-instruction: A reads 64 consecutive int4 (two full
// 512B adj-row segments); B reads 4 hT rows x 256B (padded stride, de-aliased).
// No global fragment-gathers. T14: next tile's loads issue before compute.
// Degree via ones-MFMA (exact, R4/R5-verified).
__global__ __launch_bounds__(256) void k_spmm(const int* __restrict__ adj,
                                              const unsigned short* __restrict__ hT,
                                              float* __restrict__ s_part,
                                              float* __restrict__ deg_part) {
    __shared__ unsigned short As[MT][BK + LPAD];   // As[m][k] bf16 of adj tile
    __shared__ unsigned short Bs[OUT_F][BK + LPAD];// Bs[n][k] = h[k0+k][n]

    const int tid  = threadIdx.x;
    const int lane = tid & 63;
    const int wave = tid >> 6;
    const int q    = lane >> 4;
    const int ml   = lane & 15;
    const int i0   = blockIdx.x * MT;
    const int ks   = blockIdx.y;
    const int k0   = ks * KC;

    // A staging map: int4 idx = j*256 + tid over the 64x128-int tile (32 int4/row)
    //   row = tid>>5 + 8j, col4 = tid&31  -> per-instr 64 consecutive int4 (2 rows)
    const int ar  = tid >> 5;           // 0..7
    const int ac4 = tid & 31;           // int4 index within row
    const int* ap = adj + (size_t)(i0 + ar) * N_NODES + k0 + 4 * ac4;

    // B staging map: uint4 idx = j*256 + tid over 64x128-short tile (16 uint4/row)
    //   row = tid>>4 + 16j, col8 = (tid&15)*8 shorts -> per-instr 4 rows x 256B
    const int br  = tid >> 4;           // 0..15
    const int bc8 = (tid & 15) * 8;     // short index within row
    const unsigned short* bp = hT + (size_t)br * NSTRH + k0 + bc8;

    union { bf16x8 v; unsigned short u[8]; } ones;
    #pragma unroll
    for (int i = 0; i < 8; ++i) ones.u[i] = 0x3F80;

    f32x4 acc[4], accd;
    #pragma unroll
    for (int nt = 0; nt < 4; ++nt) acc[nt] = (f32x4){0.f, 0.f, 0.f, 0.f};
    accd = (f32x4){0.f, 0.f, 0.f, 0.f};

    int4  a[8];
    uint4 b[4];

#define LOADT(s) do {                                                          \
    _Pragma("unroll")                                                          \
    for (int j = 0; j < 8; ++j)                                                \
        a[j] = *(const int4*)(ap + (size_t)8 * j * N_NODES + (s) * BK);        \
    _Pragma("unroll")                                                          \
    for (int j = 0; j < 4; ++j)                                                \
        b[j] = *(const uint4*)(bp + (size_t)16 * j * NSTRH + (s) * BK);        \
} while (0)

#define WRITET() do {                                                          \
    _Pragma("unroll")                                                          \
    for (int j = 0; j < 8; ++j) {                                              \
        unsigned int lo = ((unsigned int)a[j].x + ((unsigned int)a[j].y << 16)) * 0x3F80u; \
        unsigned int hi = ((unsigned int)a[j].z + ((unsigned int)a[j].w << 16)) * 0x3F80u; \
        unsigned int* d = (unsigned int*)&As[ar + 8 * j][4 * ac4];             \
        d[0] = lo; d[1] = hi;                                                  \
    }                                                                          \
    _Pragma("unroll")                                                          \
    for (int j = 0; j < 4; ++j)                                                \
        *(uint4*)&Bs[br + 16 * j][bc8] = b[j];                                 \
} while (0)

    // prologue: fetch tile 0 into registers
    LOADT(0);

    for (int s = 0; s < NSTEP; ++s) {
        WRITET();                      // convert + LDS write of tile s
        __syncthreads();               // tile s visible to all waves

        if (s + 1 < NSTEP) LOADT(s + 1);   // issue-early: hide HBM under MFMA phase

        #pragma unroll
        for (int kk = 0; kk < BK; kk += 32) {
            bf16x8 av = *(const bf16x8*)&As[16 * wave + ml][kk + 8 * q];
            #pragma unroll
            for (int nt = 0; nt < 4; ++nt) {
                bf16x8 bv = *(const bf16x8*)&Bs[16 * nt + ml][kk + 8 * q];
                acc[nt] = __builtin_amdgcn_mfma_f32_16x16x32_bf16(av, bv, acc[nt], 0, 0, 0);
            }
            accd = __builtin_amdgcn_mfma_f32_16x16x32_bf16(av, ones.v, accd, 0, 0, 0);
        }

        __syncthreads();               // all reads of tile s done before overwrite
    }

#undef LOADT
#undef WRITET

    // epilogue: non-atomic partial store (each block owns its 64x64 region of slice ks)
    float* sp = s_part + (size_t)ks * ((size_t)N_NODES * OUT_F);
    #pragma unroll
    for (int nt = 0; nt < 4; ++nt) {
        #pragma unroll
        for (int rr = 0; rr < 4; ++rr) {
            int orow = i0 + 16 * wave + 4 * q + rr;   // C layout: row = quad*4+reg
            int ocol = 16 * nt + ml;                  // col = lane&15
            sp[(size_t)orow * OUT_F + ocol] = acc[nt][rr];
        }
    }

    // degree: C[m][n] of ones-MFMA is row-degree in every column; take col 0 (ml==0 lanes)
    if (ml == 0) {
        #pragma unroll
        for (int rr = 0; rr < 4; ++rr)
            deg_part[ks * N_NODES + i0 + 16 * wave + 4 * q + rr] = accd[rr];
    }
}

// ---------------- kernel 3: out = elu( sum_p s_part / sum_p deg_part ), fp32
__global__ __launch_bounds__(256) void k_out(const float* __restrict__ s_part,
                                             const float* __restrict__ deg_part,
                                             float* __restrict__ out) {
    int idx = blockIdx.x * 256 + threadIdx.x;
    int i = idx >> 6;
    float s = 0.f, deg = 0.f;
    #pragma unroll
    for (int p = 0; p < KSPLIT; ++p) {
        s   += s_part[(size_t)p * ((size_t)N_NODES * OUT_F) + idx];
        deg += deg_part[p * N_NODES + i];
    }
    float v = (deg > 0.5f) ? (s / deg) : 0.f;
    out[idx] = (v > 0.f) ? v : expm1f(v);
}

extern "C" void kernel_launch(void* const* d_in, const int* in_sizes, int n_in,
                              void* d_out, int out_size, void* d_ws, size_t ws_size,
                              hipStream_t stream) {
    const int*   adj = (const int*)d_in[0];
    const float* x   = (const float*)d_in[1];   // fp32
    const float* W   = (const float*)d_in[2];   // fp32
    // d_in[3] (a) provably cancels out of the output — unused.
    float* out = (float*)d_out;                 // fp32

    char* ws = (char*)d_ws;
    const size_t hT_bytes  = (size_t)OUT_F * NSTRH * 2;                   // ~1.58 MB
    const size_t sp_bytes  = (size_t)KSPLIT * N_NODES * OUT_F * 4;        // 25.2 MB
    unsigned short* hT     = (unsigned short*)ws;
    float* s_part          = (float*)(ws + hT_bytes);
    float* deg_part        = (float*)(ws + hT_bytes + sp_bytes);
    // total ~27.2 MB of d_ws

    k_hT  <<<dim3(N_NODES / MT),          dim3(256), 0, stream>>>(x, W, hT);
    k_spmm<<<dim3(N_NODES / MT, KSPLIT),  dim3(256), 0, stream>>>(adj, hT, s_part, deg_part);
    k_out <<<dim3(N_NODES * OUT_F / 256), dim3(256), 0, stream>>>(s_part, deg_part, out);
}